// Round 1
// 187.849 us; speedup vs baseline: 1.0076x; 1.0076x over previous
//
#include <hip/hip_runtime.h>

// GlobalLocalPool: B=16, T=4096, H=512, fp32 in/out.
// out[b, 0:H]   = sum_{t < len[b]}  x[b,t,:] / max(len[b],1)
// out[b, H:2H]  = sum_{mask[b,t]}   x[b,t,:] / max(popcount(mask[b]),1)
//
// R8 lesson (kept): clamp dead-token loads to the first ALIVE token of the
// SAME 8-load burst so the duplicate request MSHR-merges with one already in
// flight; skip a burst entirely (wave-uniform) if it has no alive token.
//
// R9 (this round): timed window = 2x 512-MiB harness poison fills (~155 us)
// + ~34 us of our kernels. Only removable kernel traffic is the partial-array
// round trip: CPB 128 -> 64 halves it (16 MB -> 8 MB, ~-1.3 us) and halves
// stage-2's read. Occupancy stays at 16 waves/CU (1024 blocks x 4 waves).

constexpr int Bc = 16;
constexpr int Tc = 4096;
constexpr int Hc = 512;
constexpr int H4 = Hc / 4;             // 128 float4 per token
constexpr int CPB     = 64;            // chunk-columns per batch row
constexpr int NBLK    = Bc * CPB;      // 1024 stage-1 blocks
constexpr int ROWS_PB = CPB;           // 64 partial rows per b
constexpr int KPT     = Tc / (2 * CPB);   // 32 tokens per parity-thread
constexpr int TSTR    = 2 * CPB;          // 128-token stride between k slots
constexpr int NHALF   = KPT / 8;          // 4 bursts of 8

// ---------------- stage 1 ----------------
// Block (b,c): 256 threads; lane = tid&127 (float4 column), par = tid>>7.
// Thread handles tokens t = 2c + par + 128k, k=0..31 (wave-uniform set).
__global__ __launch_bounds__(256) void glp_partial(
    const float* __restrict__ x,
    const int* __restrict__ lengths,
    const int* __restrict__ mask,   // int32 0/1
    float* __restrict__ pg,         // [NBLK][Hc]
    float* __restrict__ pl,         // [NBLK][Hc]
    int*   __restrict__ pcnt)       // [NBLK]
{
    const int blk  = blockIdx.x;
    const int b    = blk >> 6;              // / CPB
    const int c    = blk & (CPB - 1);
    const int lane = threadIdx.x & 127;
    const int par  = __builtin_amdgcn_readfirstlane(threadIdx.x >> 7); // scalar
    const int tbase = 2 * c + par;          // uniform per wave
    const int len  = lengths[b];

    const float4* __restrict__ xb =
        (const float4*)x + ((size_t)b * Tc + tbase) * H4 + lane;
    const int* __restrict__ mrow = mask + (size_t)b * Tc + tbase;  // uniform

    float4 g = make_float4(0.f, 0.f, 0.f, 0.f);
    float4 l = make_float4(0.f, 0.f, 0.f, 0.f);

    // all 32 mask words up front (wave-uniform scalar loads, lgkm pipe)
    int m[KPT];
    #pragma unroll
    for (int k = 0; k < KPT; ++k) m[k] = mrow[k * TSTR];

    int mc = 0;
    #pragma unroll
    for (int k = 0; k < KPT; ++k) mc += (m[k] != 0);

    #pragma unroll
    for (int half = 0; half < NHALF; ++half) {
        // scalar aliveness bitmap for this burst's 8 tokens
        int ab = 0;
        #pragma unroll
        for (int j = 0; j < 8; ++j) {
            const int k = half * 8 + j;
            const int t = tbase + TSTR * k;
            ab |= (((t < len) || (m[k] != 0)) ? 1 : 0) << j;
        }
        ab = __builtin_amdgcn_readfirstlane(ab);
        if (ab == 0) continue;               // wave-uniform: no alive token here
        const int fa = __ffs(ab) - 1;        // first alive j in this burst

        float4 v[8];
        #pragma unroll
        for (int j = 0; j < 8; ++j) {
            const int k  = half * 8 + j;
            // dead -> clamp to this burst's first alive token: its request is
            // in the SAME 8-load burst, still in flight -> MSHR merge.
            const int kc = ((ab >> j) & 1) ? k : (half * 8 + fa);
            v[j] = xb[(size_t)kc * TSTR * H4];
        }
        #pragma unroll
        for (int j = 0; j < 8; ++j) {
            const int k = half * 8 + j;
            const int t = tbase + TSTR * k;
            const float wg = (t < len) ? 1.f : 0.f;
            const float wl = m[k] ? 1.f : 0.f;
            g.x = fmaf(v[j].x, wg, g.x); g.y = fmaf(v[j].y, wg, g.y);
            g.z = fmaf(v[j].z, wg, g.z); g.w = fmaf(v[j].w, wg, g.w);
            l.x = fmaf(v[j].x, wl, l.x); l.y = fmaf(v[j].y, wl, l.y);
            l.z = fmaf(v[j].z, wl, l.z); l.w = fmaf(v[j].w, wl, l.w);
        }
    }

    // combine the two parities through LDS -> one partial row per block
    __shared__ float4 sg[128];
    __shared__ float4 sl[128];
    __shared__ int smc[2];
    if (par == 1) { sg[lane] = g; sl[lane] = l; }
    if (threadIdx.x == 0)   smc[0] = mc;   // mask uniform across a parity's lanes
    if (threadIdx.x == 128) smc[1] = mc;
    __syncthreads();
    if (par == 0) {
        const float4 og = sg[lane], ol = sl[lane];
        g.x += og.x; g.y += og.y; g.z += og.z; g.w += og.w;
        l.x += ol.x; l.y += ol.y; l.z += ol.z; l.w += ol.w;
        ((float4*)(pg + (size_t)blk * Hc))[lane] = g;   // 2 KB coalesced
        ((float4*)(pl + (size_t)blk * Hc))[lane] = l;
    }
    if (threadIdx.x == 0) pcnt[blk] = smc[0] + smc[1];
}

// ---------------- stage 2: 1024 rows -> out [B, 2H] ----------------
__global__ __launch_bounds__(128) void glp_reduce(
    const float* __restrict__ pg, const float* __restrict__ pl,
    const int* __restrict__ pcnt, const int* __restrict__ lengths,
    float* __restrict__ out)
{
    const int b   = blockIdx.x >> 3;
    const int o   = blockIdx.x & 7;
    const int col = o * 16 + (threadIdx.x & 15);   // float4 column in [0,128)
    const int rg  = threadIdx.x >> 4;              // 0..7

    const float4* pg4 = (const float4*)pg;
    const float4* pl4 = (const float4*)pl;

    float4 gs = make_float4(0.f, 0.f, 0.f, 0.f);
    float4 ls = make_float4(0.f, 0.f, 0.f, 0.f);
    {
        float4 a[8], d[8];
        #pragma unroll
        for (int j = 0; j < 8; ++j) {
            const int r = b * ROWS_PB + rg + 8 * j;   // 64 rows per b
            a[j] = pg4[(size_t)r * H4 + col];
            d[j] = pl4[(size_t)r * H4 + col];
        }
        #pragma unroll
        for (int j = 0; j < 8; ++j) {
            gs.x += a[j].x; gs.y += a[j].y; gs.z += a[j].z; gs.w += a[j].w;
            ls.x += d[j].x; ls.y += d[j].y; ls.z += d[j].z; ls.w += d[j].w;
        }
    }

    __shared__ float4 lg[128], ll[128];
    lg[threadIdx.x] = gs; ll[threadIdx.x] = ls;
    __syncthreads();
    if (rg == 0) {
        #pragma unroll
        for (int j = 1; j < 8; ++j) {
            const float4 a = lg[j * 16 + (threadIdx.x & 15)];
            const float4 d = ll[j * 16 + (threadIdx.x & 15)];
            gs.x += a.x; gs.y += a.y; gs.z += a.z; gs.w += a.w;
            ls.x += d.x; ls.y += d.y; ls.z += d.z; ls.w += d.w;
        }
        int cnt = 0;
        for (int i = 0; i < ROWS_PB; ++i) cnt += pcnt[b * ROWS_PB + i]; // uniform
        const float invl = 1.f / (float)max(lengths[b], 1);
        const float invc = 1.f / (float)max(cnt, 1);
        gs.x *= invl; gs.y *= invl; gs.z *= invl; gs.w *= invl;
        ls.x *= invc; ls.y *= invc; ls.z *= invc; ls.w *= invc;
        ((float4*)out)[b * 256 + col]       = gs;   // out row = 1024 floats
        ((float4*)out)[b * 256 + 128 + col] = ls;
    }
}

// ---------------- fallback (ws too small): proven atomic path ----------------
__global__ __launch_bounds__(128) void glp_partial_atomic(
    const float* __restrict__ x, const int* __restrict__ lengths,
    const int* __restrict__ mask,
    float* __restrict__ gsum, float* __restrict__ lsum, int* __restrict__ cnt)
{
    const int blk  = blockIdx.x;
    const int b    = blk >> 6;
    const int c    = blk & 63;
    const int t0   = c * 64;
    const int lane = threadIdx.x;
    const int len  = lengths[b];
    const float4* __restrict__ xb =
        (const float4*)x + ((size_t)b * Tc + t0) * H4 + lane;
    const int* __restrict__ mb = mask + (size_t)b * Tc + t0;

    float4 g = make_float4(0.f, 0.f, 0.f, 0.f);
    float4 l = make_float4(0.f, 0.f, 0.f, 0.f);
    int mc = 0;
    for (int ii = 0; ii < 64; ii += 8) {
        float4 v[8]; int m[8];
        #pragma unroll
        for (int j = 0; j < 8; ++j) { v[j] = xb[(size_t)(ii + j) * H4]; m[j] = mb[ii + j]; }
        #pragma unroll
        for (int j = 0; j < 8; ++j) {
            const float wg = (t0 + ii + j < len) ? 1.f : 0.f;
            const float wl = m[j] ? 1.f : 0.f;
            g.x = fmaf(v[j].x, wg, g.x); g.y = fmaf(v[j].y, wg, g.y);
            g.z = fmaf(v[j].z, wg, g.z); g.w = fmaf(v[j].w, wg, g.w);
            l.x = fmaf(v[j].x, wl, l.x); l.y = fmaf(v[j].y, wl, l.y);
            l.z = fmaf(v[j].z, wl, l.z); l.w = fmaf(v[j].w, wl, l.w);
            mc += (m[j] != 0);
        }
    }
    float* gp = gsum + b * Hc + lane * 4;
    float* lp = lsum + b * Hc + lane * 4;
    atomicAdd(gp + 0, g.x); atomicAdd(gp + 1, g.y);
    atomicAdd(gp + 2, g.z); atomicAdd(gp + 3, g.w);
    atomicAdd(lp + 0, l.x); atomicAdd(lp + 1, l.y);
    atomicAdd(lp + 2, l.z); atomicAdd(lp + 3, l.w);
    if (lane == 0) atomicAdd(cnt + b, mc);
}

__global__ __launch_bounds__(512) void glp_finalize(
    const float* __restrict__ gsum, const float* __restrict__ lsum,
    const int* __restrict__ cnt, const int* __restrict__ lengths,
    float* __restrict__ out)
{
    const int b = blockIdx.x;
    const int h = threadIdx.x;
    out[b * 2 * Hc + h]      = gsum[b * Hc + h] / (float)max(lengths[b], 1);
    out[b * 2 * Hc + Hc + h] = lsum[b * Hc + h] / (float)max(cnt[b], 1);
}

extern "C" void kernel_launch(void* const* d_in, const int* in_sizes, int n_in,
                              void* d_out, int out_size, void* d_ws, size_t ws_size,
                              hipStream_t stream) {
    const float* x     = (const float*)d_in[0];
    const int* lengths = (const int*)d_in[1];
    const int* mask    = (const int*)d_in[2];   // bool promoted to int32 by harness
    float* out = (float*)d_out;

    const size_t npg  = (size_t)NBLK * Hc;  // floats per partial array
    const size_t need = 2 * npg * sizeof(float) + NBLK * sizeof(int);
    if (ws_size >= need) {
        float* pg   = (float*)d_ws;
        float* pl   = pg + npg;
        int*   pcnt = (int*)(pl + npg);
        glp_partial<<<NBLK, 256, 0, stream>>>(x, lengths, mask, pg, pl, pcnt);
        glp_reduce<<<Bc * 8, 128, 0, stream>>>(pg, pl, pcnt, lengths, out);
    } else {
        float* gsum = (float*)d_ws;
        float* lsum = gsum + Bc * Hc;
        int*   cnt  = (int*)(lsum + Bc * Hc);
        const size_t zb = (size_t)(2 * Bc * Hc) * sizeof(float) + Bc * sizeof(int);
        hipMemsetAsync(d_ws, 0, zb, stream);
        glp_partial_atomic<<<Bc * 64, 128, 0, stream>>>(x, lengths, mask, gsum, lsum, cnt);
        glp_finalize<<<Bc, Hc, 0, stream>>>(gsum, lsum, cnt, lengths, out);
    }
}